// Round 3
// baseline (92.270 us; speedup 1.0000x reference)
//
#include <hip/hip_runtime.h>
#include <hip/hip_bf16.h>
#include <math.h>

// Problem constants
#define P_TOTAL 18378
// param breakpoints (floats): w1 [0,400), b1 [400,416), w2 [416,13216),
// b2 [13216,13248), w3 [13248,18368), b3 [18368,18378)

typedef __attribute__((ext_vector_type(8))) short short8;
typedef __attribute__((ext_vector_type(4))) float float4v;
typedef __attribute__((ext_vector_type(16))) float float16;

// single-instruction bf16 convert (RNE, bit-identical to manual round-to-nearest-even)
__device__ __forceinline__ unsigned short f2bf(float f) {
    unsigned r;
    asm("v_cvt_pk_bf16_f32 %0, %1, %1" : "=v"(r) : "v"(f));
    return (unsigned short)r;
}

// DPP wave64 sum-reduction, result valid in lane 63 (row_shr 1/2/4/8 + row_bcast 15/31).
#define DPP_ADD_STEP(x, ctrl)                                                  \
    x += __int_as_float(__builtin_amdgcn_update_dpp(                           \
            0, __float_as_int(x), ctrl, 0xf, 0xf, true))

__device__ __forceinline__ float wave_reduce_sum63(float x) {
    DPP_ADD_STEP(x, 0x111);   // row_shr:1
    DPP_ADD_STEP(x, 0x112);   // row_shr:2
    DPP_ADD_STEP(x, 0x114);   // row_shr:4
    DPP_ADD_STEP(x, 0x118);   // row_shr:8  -> lane 15+16k holds row sum
    DPP_ADD_STEP(x, 0x142);   // row_bcast:15 -> lanes 31,63 hold half sums
    DPP_ADD_STEP(x, 0x143);   // row_bcast:31 -> lane 63 holds total
    return x;
}

// ---------------- Kernel 0: prep ----------------
// R16: software-pipelined. Weight blocks: 2304 = 9*256 exactly -> 9
// compile-time iterations, ALL 9 loads issued before any convert/store
// (w2/w3/w1 source reads; scatter is on the store side). Breaks the
// load->store serial latency chain (~9x900cy -> ~900cy + throughput).
// Im2col: image load software-pipelined the same way.
// Layouts unchanged:
//   wswz[i][tap][co32][cin16] bf16, w1bf[i][co16][32pad] bf16,
//   w3lf[i][o10][lane64][slot8] f32 (mega's dense permutation),
//   Bmat[j][576 c][32 k] bf16 im2col.
__global__ __launch_bounds__(256) void prep_kernel(
        const float* __restrict__ params,
        const float* __restrict__ batch,
        unsigned short* __restrict__ wswz,
        float* __restrict__ w3lf,
        unsigned short* __restrict__ w1bf,
        unsigned short* __restrict__ Bmat) {
    int blk = blockIdx.x;
    int t = threadIdx.x;
    if (blk < 512) {
        // ---- weight prep: init i, part p covers s in [p*2304, (p+1)*2304) ----
        int i = blk >> 3;
        int p = blk & 7;
        const float* P = params + (size_t)i * P_TOTAL;
        int sbase = p * 2304 + t;
        float v[9];
#pragma unroll
        for (int it = 0; it < 9; ++it) {       // issue all 9 loads first
            int s = sbase + it * 256;
            int si;
            if (s < 12800) {
                si = 416 + s;                  // w2 read is linear
            } else if (s < 17920) {
                int k = s - 12800;             // w3 gather (permuted read)
                int o = k >> 9, r = k & 511;
                int l = r >> 3, sl = r & 7;
                int co = l & 31, h = l >> 5;
                int py = sl >> 1, d = sl & 1;
                si = 13248 + o * 512 + co * 16 + py * 4 + 2 * h + d;
            } else {
                int e = s - 17920;             // w1 (clamped; zeroed at store)
                int m = e >> 5, k = e & 31;
                si = m * 25 + (k < 25 ? k : 24);
            }
            v[it] = P[si];
        }
#pragma unroll
        for (int it = 0; it < 9; ++it) {       // converts + scattered stores
            int s = sbase + it * 256;
            if (s < 12800) {
                int co = s / 400;
                int r = s - co * 400;
                int cin = r / 25;
                int sk = r - cin * 25;         // sk = ky*5+kx
                wswz[(size_t)i * 12800 + (sk * 32 + co) * 16 + cin] = f2bf(v[it]);
            } else if (s < 17920) {
                w3lf[(size_t)i * 5120 + (s - 12800)] = v[it];
            } else {
                int e = s - 17920;
                int k = e & 31;
                w1bf[(size_t)i * 512 + e] =
                    (k < 25) ? f2bf(v[it]) : (unsigned short)0;
            }
        }
    } else {
        // ---- image im2col: 2 blocks per image ----
        __shared__ float img[784];
        int jb = blk - 512;
        int j = jb >> 1;
        int half = jb & 1;
        const float* ip = batch + j * 784;
        float iv[4];
#pragma unroll
        for (int it = 0; it < 4; ++it) {       // pipeline the image load
            int k = t + it * 256;
            iv[it] = (k < 784) ? ip[k] : 0.f;
        }
#pragma unroll
        for (int it = 0; it < 4; ++it) {
            int k = t + it * 256;
            if (k < 784) img[k] = iv[it];
        }
        __syncthreads();
        unsigned short* dst = Bmat + (size_t)j * 18432;
        int task0 = half * 1152;
        for (int task = task0 + t; task < task0 + 1152; task += 256) {
            int c = task >> 2, kh = task & 3;
            int pp = c >> 2, q = c & 3;
            int py = pp / 12, px = pp - py * 12;
            int y0 = 2 * py + (q >> 1);
            int x0 = 2 * px + (q & 1);
            unsigned short ov[8] __attribute__((aligned(16)));
#pragma unroll
            for (int u = 0; u < 8; ++u) {
                int k = kh * 8 + u;
                float v = 0.f;
                if (k < 25) {
                    int ky = k / 5, kx = k - ky * 5;
                    v = img[(y0 + ky) * 28 + x0 + kx];
                }
                ov[u] = f2bf(v);
            }
            *(uint4*)(dst + c * 32 + kh * 8) = *(const uint4*)ov;
        }
    }
}

// ---------------- Kernel 1 (mega): conv1 + conv2 + pool + dense + log_softmax ----------------
// R16 on top of R15:
// (a) G-FAST dispatch swizzle (i = b>>4, g = b&15). XCD = b&7 = g&7 ->
//     per-XCD working set = 16 images' Bmat (0.58 MB) + all weights (2.9 MB)
//     = 3.5 MB < 4 MB L2 (was: all 128 images = 5 MB, L3 streaming). Per-CU,
//     the 4 resident blocks (b, b+256, ...) share g (256%16==0) -> same 8
//     images -> Bmat reads L1-shared 4x (was: same init, disjoint images).
// (b) conv1 manual 6x6 batching: 12 independent global loads in flight.
// Wave = 2 images of same init (in-register weight amortization, R15).
// LDS slice: exact stride 16 + XOR swizzle elem ^= ((pix>>2)&7)<<3, 4608 B;
// 8 slices = 36.9 KB, 4 blocks/CU. BARRIER-FREE.
#define A1_SLICE 2304           // elems (4608 B) per (wave,image) slice
__global__ __launch_bounds__(256, 4) void mega_kernel(
        const float* __restrict__ params,
        const unsigned short* __restrict__ Bmat,   // [img][576][32] bf16 im2col
        const unsigned short* __restrict__ w1bf,   // [init][16][32] bf16
        const unsigned short* __restrict__ wswz,   // [init][25][32][16] bf16
        const float* __restrict__ w3lf,            // [init][10][64][8] f32 (permuted)
        float* __restrict__ out) {                 // [init][img][10] f32
    __shared__ unsigned short a1s[8 * A1_SLICE];   // 36864 B
    int b = blockIdx.x;
    int i = b >> 4;           // init (slow dim)
    int g = b & 15;           // image group of 8 (fast dim -> XCD/L1 locality)
    int t = threadIdx.x;
    int w = t >> 6;           // wave
    int lane = t & 63;
    int j0 = g * 8 + w;       // image A
    int j1 = j0 + 4;          // image B

    unsigned short* s0 = a1s + w * (2 * A1_SLICE);
    unsigned short* s1 = s0 + A1_SLICE;

    // ---- Phase A: conv1 for (i, j0) and (i, j1); weights loaded ONCE ----
    {
        int co = lane & 15;       // A row (pixel-in-group) AND conv1 out-channel
        int h4 = lane >> 4;       // k-half / pool-quad row group
        short8 wfr = *(const short8*)(w1bf + (size_t)i * 512 + co * 32 + h4 * 8);
        float bias1 = params[(size_t)i * P_TOTAL + 400 + co];
        const unsigned short* ba = Bmat + (size_t)j0 * 18432;
        const unsigned short* bb = Bmat + (size_t)j1 * 18432;
        int ebase = h4 * 16 + co;     // elem = ebase + nt*64, swizzle ^ (nt&7)<<3
#pragma unroll
        for (int gB = 0; gB < 6; ++gB) {
            short8 fa[6], fb[6];
#pragma unroll
            for (int u = 0; u < 6; ++u) {      // 12 loads in flight
                int nt = gB * 6 + u;
                fa[u] = *(const short8*)(ba + (nt * 16 + co) * 32 + h4 * 8);
                fb[u] = *(const short8*)(bb + (nt * 16 + co) * 32 + h4 * 8);
            }
#pragma unroll
            for (int u = 0; u < 6; ++u) {
                int nt = gB * 6 + u;
                float4v acca = {0.f, 0.f, 0.f, 0.f};
                float4v accb = {0.f, 0.f, 0.f, 0.f};
                acca = __builtin_amdgcn_mfma_f32_16x16x32_bf16(fa[u], wfr, acca, 0, 0, 0);
                accb = __builtin_amdgcn_mfma_f32_16x16x32_bf16(fb[u], wfr, accb, 0, 0, 0);
                float va = fmaxf(fmaxf(acca[0], acca[1]), fmaxf(acca[2], acca[3]));
                float vb = fmaxf(fmaxf(accb[0], accb[1]), fmaxf(accb[2], accb[3]));
                va = fmaxf(va + bias1, 0.f);
                vb = fmaxf(vb + bias1, 0.f);
                int e = (ebase + nt * 64) ^ ((nt & 7) << 3);   // XOR compile-time
                s0[e] = f2bf(va);    // pix = nt*4+h4
                s1[e] = f2bf(vb);
            }
        }
    }
    // no barrier: each wave reads only its own writes (DS program order)

    // ---- Phase B: conv2 for both images; 1 weight load feeds 4 MFMAs ----
    int n = lane & 31;        // A row = pixel ; B col = co
    int h = lane >> 5;        // k-half
    const short8* wg = (const short8*)(wswz + (size_t)i * 12800 + n * 16 + h * 8);
    int y0 = n >> 3, x0 = n & 7;
    int pixbase = y0 * 12 + x0;
    int h8 = h * 8;

    float16 acc0a = {};   // img j0, pixels 0..31 (y 0..3)
    float16 acc1a = {};   // img j0, pixels 48..  (y 4..7)
    float16 acc0b = {};   // img j1
    float16 acc1b = {};
    __builtin_amdgcn_s_setprio(1);
#pragma unroll
    for (int ky = 0; ky < 5; ++ky) {
#pragma unroll
        for (int kx = 0; kx < 5; ++kx) {
            int tap = ky * 5 + kx;
            short8 wf = wg[tap * 64];               // 1 KB tap matrix (L2)
            int plo = pixbase + ky * 12 + kx;
            int phi = plo + 48;
            int elo = (plo * 16 + h8) ^ (((plo >> 2) & 7) << 3);
            int ehi = (phi * 16 + h8) ^ (((phi >> 2) & 7) << 3);
            short8 p0a = *(const short8*)(s0 + elo);
            short8 p1a = *(const short8*)(s0 + ehi);
            short8 p0b = *(const short8*)(s1 + elo);   // same offsets, other slice
            short8 p1b = *(const short8*)(s1 + ehi);
            acc0a = __builtin_amdgcn_mfma_f32_32x32x16_bf16(p0a, wf, acc0a, 0, 0, 0);
            acc1a = __builtin_amdgcn_mfma_f32_32x32x16_bf16(p1a, wf, acc1a, 0, 0, 0);
            acc0b = __builtin_amdgcn_mfma_f32_32x32x16_bf16(p0b, wf, acc0b, 0, 0, 0);
            acc1b = __builtin_amdgcn_mfma_f32_32x32x16_bf16(p1b, wf, acc1b, 0, 0, 0);
        }
    }
    __builtin_amdgcn_s_setprio(0);

    // ---- Phase C: in-register 2x2 pool + bias + ReLU, both images ----
    // row r = (reg&3) + 8*(reg>>2) + 4h -> pixel (y = p>>3, x = p&7).
    // pooled (pyl,d): regs {base, base+1, base+4, base+5}, base = pyl*8 + d*2.
    // lane (co = lane&31, h) ends with 8 features f = co*16 + py*4 + 2h + d,
    // slot s = py*2 + d  — matches w3lf's prep permutation.
    int co2 = lane & 31;
    float bias2 = params[(size_t)i * P_TOTAL + 13216 + co2];
    float xra[8], xrb[8];
#pragma unroll
    for (int pyl = 0; pyl < 2; ++pyl) {
#pragma unroll
        for (int d = 0; d < 2; ++d) {
            int base = pyl * 8 + d * 2;
            float v0 = fmaxf(fmaxf(acc0a[base], acc0a[base + 1]),
                             fmaxf(acc0a[base + 4], acc0a[base + 5]));
            float v1 = fmaxf(fmaxf(acc1a[base], acc1a[base + 1]),
                             fmaxf(acc1a[base + 4], acc1a[base + 5]));
            xra[pyl * 2 + d]     = fmaxf(v0 + bias2, 0.f);   // py = pyl
            xra[4 + pyl * 2 + d] = fmaxf(v1 + bias2, 0.f);   // py = 2+pyl
            v0 = fmaxf(fmaxf(acc0b[base], acc0b[base + 1]),
                       fmaxf(acc0b[base + 4], acc0b[base + 5]));
            v1 = fmaxf(fmaxf(acc1b[base], acc1b[base + 1]),
                       fmaxf(acc1b[base + 4], acc1b[base + 5]));
            xrb[pyl * 2 + d]     = fmaxf(v0 + bias2, 0.f);
            xrb[4 + pyl * 2 + d] = fmaxf(v1 + bias2, 0.f);
        }
    }

    // ---- dense (10x512) + log_softmax; w3 loads shared by both images ----
    const float* w3p = w3lf + (size_t)i * 5120 + lane * 8;
    float aa[10], ab[10];
#pragma unroll
    for (int o = 0; o < 10; ++o) {
        float4v u0 = *(const float4v*)(w3p + o * 512);
        float4v u1 = *(const float4v*)(w3p + o * 512 + 4);
        float ra = 0.f, rb = 0.f;
        ra = fmaf(xra[0], u0[0], ra);  rb = fmaf(xrb[0], u0[0], rb);
        ra = fmaf(xra[1], u0[1], ra);  rb = fmaf(xrb[1], u0[1], rb);
        ra = fmaf(xra[2], u0[2], ra);  rb = fmaf(xrb[2], u0[2], rb);
        ra = fmaf(xra[3], u0[3], ra);  rb = fmaf(xrb[3], u0[3], rb);
        ra = fmaf(xra[4], u1[0], ra);  rb = fmaf(xrb[4], u1[0], rb);
        ra = fmaf(xra[5], u1[1], ra);  rb = fmaf(xrb[5], u1[1], rb);
        ra = fmaf(xra[6], u1[2], ra);  rb = fmaf(xrb[6], u1[2], rb);
        ra = fmaf(xra[7], u1[3], ra);  rb = fmaf(xrb[7], u1[3], rb);
        aa[o] = wave_reduce_sum63(ra);   // independent 6-step DPP chains
        ab[o] = wave_reduce_sum63(rb);
    }
    if (lane == 63) {
        const float* bp = params + (size_t)i * P_TOTAL + 18368;
        float m = -3.4e38f;
#pragma unroll
        for (int o = 0; o < 10; ++o) { aa[o] += bp[o]; m = fmaxf(m, aa[o]); }
        float ssum = 0.f;
#pragma unroll
        for (int o = 0; o < 10; ++o) ssum += __expf(aa[o] - m);
        float ls = __logf(ssum) + m;
        float* op = out + ((size_t)i * 128 + j0) * 10;
#pragma unroll
        for (int o = 0; o < 10; ++o) op[o] = aa[o] - ls;

        m = -3.4e38f;
#pragma unroll
        for (int o = 0; o < 10; ++o) { ab[o] += bp[o]; m = fmaxf(m, ab[o]); }
        ssum = 0.f;
#pragma unroll
        for (int o = 0; o < 10; ++o) ssum += __expf(ab[o] - m);
        ls = __logf(ssum) + m;
        op = out + ((size_t)i * 128 + j1) * 10;
#pragma unroll
        for (int o = 0; o < 10; ++o) op[o] = ab[o] - ls;
    }
}

extern "C" void kernel_launch(void* const* d_in, const int* in_sizes, int n_in,
                              void* d_out, int out_size, void* d_ws, size_t ws_size,
                              hipStream_t stream) {
    const float* params = (const float*)d_in[0];   // (64, 18378) fp32
    const float* batch  = (const float*)d_in[1];   // (128, 1, 28, 28) fp32
    float* out = (float*)d_out;                    // (64, 128, 10) fp32

    // workspace (16B-aligned sections):
    //   wswz 64*12800 bf16 = 1,638,400 B
    //   w3lf 64*5120  f32  = 1,310,720 B
    //   w1bf 64*512   bf16 =    65,536 B
    //   Bmat 128*18432 bf16 = 4,718,592 B
    unsigned short* wswz = (unsigned short*)d_ws;
    float* w3lf = (float*)((char*)d_ws + 1638400);
    unsigned short* w1bf = (unsigned short*)((char*)d_ws + 1638400 + 1310720);
    unsigned short* Bmat = (unsigned short*)((char*)d_ws + 1638400 + 1310720 + 65536);

    prep_kernel<<<768, 256, 0, stream>>>(params, batch, wswz, w3lf, w1bf, Bmat);
    // R16 grid: 1024 blocks = 64 inits x 16 image-groups(8), G-FAST (g = b&15);
    // 4 waves/block, each wave = 2 images; 4 blocks/CU (LDS 36.9 KB, VGPR<=128).
    mega_kernel<<<1024, 256, 0, stream>>>(params, Bmat, w1bf, wswz, w3lf, out);
}

// Round 6
// 89.928 us; speedup vs baseline: 1.0260x; 1.0260x over previous
//
#include <hip/hip_runtime.h>
#include <hip/hip_bf16.h>
#include <math.h>

// Problem constants
#define P_TOTAL 18378
// param breakpoints (floats): w1 [0,400), b1 [400,416), w2 [416,13216),
// b2 [13216,13248), w3 [13248,18368), b3 [18368,18378)

typedef __attribute__((ext_vector_type(8))) short short8;
typedef __attribute__((ext_vector_type(4))) float float4v;
typedef __attribute__((ext_vector_type(16))) float float16;

// single-instruction bf16 convert (RNE, bit-identical to manual round-to-nearest-even)
__device__ __forceinline__ unsigned short f2bf(float f) {
    unsigned r;
    asm("v_cvt_pk_bf16_f32 %0, %1, %1" : "=v"(r) : "v"(f));
    return (unsigned short)r;
}

// 3-input max. Plain C form: clang fuses nested fmaxf into v_max3_f32 on
// gfx9+ (R18: replaced R17's inline-asm version — the only never-benched
// construct in the twice-failed R17 build; fmax is rounding-free so this
// is bitwise-identical either way).
__device__ __forceinline__ float fmax3(float a, float b, float c) {
    return fmaxf(fmaxf(a, b), c);
}

// DPP wave64 sum-reduction, result valid in lane 63 (row_shr 1/2/4/8 + row_bcast 15/31).
#define DPP_ADD_STEP(x, ctrl)                                                  \
    x += __int_as_float(__builtin_amdgcn_update_dpp(                           \
            0, __float_as_int(x), ctrl, 0xf, 0xf, true))

__device__ __forceinline__ float wave_reduce_sum63(float x) {
    DPP_ADD_STEP(x, 0x111);   // row_shr:1
    DPP_ADD_STEP(x, 0x112);   // row_shr:2
    DPP_ADD_STEP(x, 0x114);   // row_shr:4
    DPP_ADD_STEP(x, 0x118);   // row_shr:8  -> lane 15+16k holds row sum
    DPP_ADD_STEP(x, 0x142);   // row_bcast:15 -> lanes 31,63 hold half sums
    DPP_ADD_STEP(x, 0x143);   // row_bcast:31 -> lane 63 holds total
    return x;
}

// ---------------- Kernel 0: prep (R16 pipelined version, kept) ----------------
// Weight blocks: 2304 = 9*256 -> 9 compile-time iterations, ALL 9 loads
// issued before any convert/store. Im2col: image load software-pipelined.
// Layouts:
//   wswz[i][tap][co32][cin16] bf16, w1bf[i][co16][32pad] bf16,
//   w3lf[i][o10][lane64][slot8] f32 (mega's dense permutation),
//   Bmat[j][576 c][32 k] bf16 im2col.
__global__ __launch_bounds__(256) void prep_kernel(
        const float* __restrict__ params,
        const float* __restrict__ batch,
        unsigned short* __restrict__ wswz,
        float* __restrict__ w3lf,
        unsigned short* __restrict__ w1bf,
        unsigned short* __restrict__ Bmat) {
    int blk = blockIdx.x;
    int t = threadIdx.x;
    if (blk < 512) {
        // ---- weight prep: init i, part p covers s in [p*2304, (p+1)*2304) ----
        int i = blk >> 3;
        int p = blk & 7;
        const float* P = params + (size_t)i * P_TOTAL;
        int sbase = p * 2304 + t;
        float v[9];
#pragma unroll
        for (int it = 0; it < 9; ++it) {       // issue all 9 loads first
            int s = sbase + it * 256;
            int si;
            if (s < 12800) {
                si = 416 + s;                  // w2 read is linear
            } else if (s < 17920) {
                int k = s - 12800;             // w3 gather (permuted read)
                int o = k >> 9, r = k & 511;
                int l = r >> 3, sl = r & 7;
                int co = l & 31, h = l >> 5;
                int py = sl >> 1, d = sl & 1;
                si = 13248 + o * 512 + co * 16 + py * 4 + 2 * h + d;
            } else {
                int e = s - 17920;             // w1 (clamped; zeroed at store)
                int m = e >> 5, k = e & 31;
                si = m * 25 + (k < 25 ? k : 24);
            }
            v[it] = P[si];
        }
#pragma unroll
        for (int it = 0; it < 9; ++it) {       // converts + scattered stores
            int s = sbase + it * 256;
            if (s < 12800) {
                int co = s / 400;
                int r = s - co * 400;
                int cin = r / 25;
                int sk = r - cin * 25;         // sk = ky*5+kx
                wswz[(size_t)i * 12800 + (sk * 32 + co) * 16 + cin] = f2bf(v[it]);
            } else if (s < 17920) {
                w3lf[(size_t)i * 5120 + (s - 12800)] = v[it];
            } else {
                int e = s - 17920;
                int k = e & 31;
                w1bf[(size_t)i * 512 + e] =
                    (k < 25) ? f2bf(v[it]) : (unsigned short)0;
            }
        }
    } else {
        // ---- image im2col: 2 blocks per image ----
        __shared__ float img[784];
        int jb = blk - 512;
        int j = jb >> 1;
        int half = jb & 1;
        const float* ip = batch + j * 784;
        float iv[4];
#pragma unroll
        for (int it = 0; it < 4; ++it) {       // pipeline the image load
            int k = t + it * 256;
            iv[it] = (k < 784) ? ip[k] : 0.f;
        }
#pragma unroll
        for (int it = 0; it < 4; ++it) {
            int k = t + it * 256;
            if (k < 784) img[k] = iv[it];
        }
        __syncthreads();
        unsigned short* dst = Bmat + (size_t)j * 18432;
        int task0 = half * 1152;
        for (int task = task0 + t; task < task0 + 1152; task += 256) {
            int c = task >> 2, kh = task & 3;
            int pp = c >> 2, q = c & 3;
            int py = pp / 12, px = pp - py * 12;
            int y0 = 2 * py + (q >> 1);
            int x0 = 2 * px + (q & 1);
            unsigned short ov[8] __attribute__((aligned(16)));
#pragma unroll
            for (int u = 0; u < 8; ++u) {
                int k = kh * 8 + u;
                float v = 0.f;
                if (k < 25) {
                    int ky = k / 5, kx = k - ky * 5;
                    v = img[(y0 + ky) * 28 + x0 + kx];
                }
                ov[u] = f2bf(v);
            }
            *(uint4*)(dst + c * 32 + kh * 8) = *(const uint4*)ov;
        }
    }
}

// ---------------- Kernel 1 (mega): conv1 + conv2 + pool + dense + log_softmax ----------------
// R18 = R17 with compiler-generated max3 (no new inline asm): i-fast dispatch
// (R15's measured-best mapping), wave = 2 images of same init (R15), conv1
// 6x6 load batching (R16), pipelined prep (R16), fmax3 via nested fmaxf
// (clang fuses to v_max3_f32) at all 88 max-of-4 sites.
// LDS slice: exact stride 16 + XOR swizzle elem ^= ((pix>>2)&7)<<3, 4608 B;
// 8 slices = 36.9 KB, 4 blocks/CU. BARRIER-FREE.
#define A1_SLICE 2304           // elems (4608 B) per (wave,image) slice
__global__ __launch_bounds__(256, 4) void mega_kernel(
        const float* __restrict__ params,
        const unsigned short* __restrict__ Bmat,   // [img][576][32] bf16 im2col
        const unsigned short* __restrict__ w1bf,   // [init][16][32] bf16
        const unsigned short* __restrict__ wswz,   // [init][25][32][16] bf16
        const float* __restrict__ w3lf,            // [init][10][64][8] f32 (permuted)
        float* __restrict__ out) {                 // [init][img][10] f32
    __shared__ unsigned short a1s[8 * A1_SLICE];   // 36864 B
    int b = blockIdx.x;
    int i = b & 63;           // init  (fast dim -> XCD-local weight residency)
    int g = b >> 6;           // image group of 8 (slow dim)
    int t = threadIdx.x;
    int w = t >> 6;           // wave
    int lane = t & 63;
    int j0 = g * 8 + w;       // image A
    int j1 = j0 + 4;          // image B

    unsigned short* s0 = a1s + w * (2 * A1_SLICE);
    unsigned short* s1 = s0 + A1_SLICE;

    // ---- Phase A: conv1 for (i, j0) and (i, j1); weights loaded ONCE ----
    {
        int co = lane & 15;       // conv1 out-channel = conv2 cin
        int h4 = lane >> 4;       // k-half / pool-quad row group
        short8 wfr = *(const short8*)(w1bf + (size_t)i * 512 + co * 32 + h4 * 8);
        float bias1 = params[(size_t)i * P_TOTAL + 400 + co];
        const unsigned short* ba = Bmat + (size_t)j0 * 18432;
        const unsigned short* bb = Bmat + (size_t)j1 * 18432;
        int ebase = h4 * 16 + co;     // elem = ebase + nt*64, swizzle ^ (nt&7)<<3
#pragma unroll
        for (int gB = 0; gB < 6; ++gB) {
            short8 fa[6], fb[6];
#pragma unroll
            for (int u = 0; u < 6; ++u) {      // 12 loads in flight
                int nt = gB * 6 + u;
                fa[u] = *(const short8*)(ba + (nt * 16 + co) * 32 + h4 * 8);
                fb[u] = *(const short8*)(bb + (nt * 16 + co) * 32 + h4 * 8);
            }
#pragma unroll
            for (int u = 0; u < 6; ++u) {
                int nt = gB * 6 + u;
                float4v acca = {0.f, 0.f, 0.f, 0.f};
                float4v accb = {0.f, 0.f, 0.f, 0.f};
                acca = __builtin_amdgcn_mfma_f32_16x16x32_bf16(fa[u], wfr, acca, 0, 0, 0);
                accb = __builtin_amdgcn_mfma_f32_16x16x32_bf16(fb[u], wfr, accb, 0, 0, 0);
                float va = fmaxf(fmax3(acca[0], acca[1], acca[2]), acca[3]);
                float vb = fmaxf(fmax3(accb[0], accb[1], accb[2]), accb[3]);
                va = fmaxf(va + bias1, 0.f);
                vb = fmaxf(vb + bias1, 0.f);
                int e = (ebase + nt * 64) ^ ((nt & 7) << 3);   // XOR compile-time
                s0[e] = f2bf(va);    // pix = nt*4+h4
                s1[e] = f2bf(vb);
            }
        }
    }
    // no barrier: each wave reads only its own writes (DS program order)

    // ---- Phase B: conv2 for both images; 1 weight load feeds 4 MFMAs ----
    int n = lane & 31;        // A row = pixel ; B col = co
    int h = lane >> 5;        // k-half
    const short8* wg = (const short8*)(wswz + (size_t)i * 12800 + n * 16 + h * 8);
    int y0 = n >> 3, x0 = n & 7;
    int pixbase = y0 * 12 + x0;
    int h8 = h * 8;

    float16 acc0a = {};   // img j0, pixels 0..31 (y 0..3)
    float16 acc1a = {};   // img j0, pixels 48..  (y 4..7)
    float16 acc0b = {};   // img j1
    float16 acc1b = {};
    __builtin_amdgcn_s_setprio(1);
#pragma unroll
    for (int ky = 0; ky < 5; ++ky) {
#pragma unroll
        for (int kx = 0; kx < 5; ++kx) {
            int tap = ky * 5 + kx;
            short8 wf = wg[tap * 64];               // 1 KB tap matrix (L2)
            int plo = pixbase + ky * 12 + kx;
            int phi = plo + 48;
            int elo = (plo * 16 + h8) ^ (((plo >> 2) & 7) << 3);
            int ehi = (phi * 16 + h8) ^ (((phi >> 2) & 7) << 3);
            short8 p0a = *(const short8*)(s0 + elo);
            short8 p1a = *(const short8*)(s0 + ehi);
            short8 p0b = *(const short8*)(s1 + elo);   // same offsets, other slice
            short8 p1b = *(const short8*)(s1 + ehi);
            acc0a = __builtin_amdgcn_mfma_f32_32x32x16_bf16(p0a, wf, acc0a, 0, 0, 0);
            acc1a = __builtin_amdgcn_mfma_f32_32x32x16_bf16(p1a, wf, acc1a, 0, 0, 0);
            acc0b = __builtin_amdgcn_mfma_f32_32x32x16_bf16(p0b, wf, acc0b, 0, 0, 0);
            acc1b = __builtin_amdgcn_mfma_f32_32x32x16_bf16(p1b, wf, acc1b, 0, 0, 0);
        }
    }
    __builtin_amdgcn_s_setprio(0);

    // ---- Phase C: in-register 2x2 pool + bias + ReLU, both images ----
    // row r = (reg&3) + 8*(reg>>2) + 4h -> pixel (y = p>>3, x = p&7).
    // pooled (pyl,d): regs {base, base+1, base+4, base+5}, base = pyl*8 + d*2.
    // lane (co = lane&31, h) ends with 8 features f = co*16 + py*4 + 2h + d,
    // slot s = py*2 + d  — matches w3lf's prep permutation.
    int co2 = lane & 31;
    float bias2 = params[(size_t)i * P_TOTAL + 13216 + co2];
    float xra[8], xrb[8];
#pragma unroll
    for (int pyl = 0; pyl < 2; ++pyl) {
#pragma unroll
        for (int d = 0; d < 2; ++d) {
            int base = pyl * 8 + d * 2;
            float v0 = fmaxf(fmax3(acc0a[base], acc0a[base + 1], acc0a[base + 4]),
                             acc0a[base + 5]);
            float v1 = fmaxf(fmax3(acc1a[base], acc1a[base + 1], acc1a[base + 4]),
                             acc1a[base + 5]);
            xra[pyl * 2 + d]     = fmaxf(v0 + bias2, 0.f);   // py = pyl
            xra[4 + pyl * 2 + d] = fmaxf(v1 + bias2, 0.f);   // py = 2+pyl
            v0 = fmaxf(fmax3(acc0b[base], acc0b[base + 1], acc0b[base + 4]),
                       acc0b[base + 5]);
            v1 = fmaxf(fmax3(acc1b[base], acc1b[base + 1], acc1b[base + 4]),
                       acc1b[base + 5]);
            xrb[pyl * 2 + d]     = fmaxf(v0 + bias2, 0.f);
            xrb[4 + pyl * 2 + d] = fmaxf(v1 + bias2, 0.f);
        }
    }

    // ---- dense (10x512) + log_softmax; w3 loads shared by both images ----
    const float* w3p = w3lf + (size_t)i * 5120 + lane * 8;
    float aa[10], ab[10];
#pragma unroll
    for (int o = 0; o < 10; ++o) {
        float4v u0 = *(const float4v*)(w3p + o * 512);
        float4v u1 = *(const float4v*)(w3p + o * 512 + 4);
        float ra = 0.f, rb = 0.f;
        ra = fmaf(xra[0], u0[0], ra);  rb = fmaf(xrb[0], u0[0], rb);
        ra = fmaf(xra[1], u0[1], ra);  rb = fmaf(xrb[1], u0[1], rb);
        ra = fmaf(xra[2], u0[2], ra);  rb = fmaf(xrb[2], u0[2], rb);
        ra = fmaf(xra[3], u0[3], ra);  rb = fmaf(xrb[3], u0[3], rb);
        ra = fmaf(xra[4], u1[0], ra);  rb = fmaf(xrb[4], u1[0], rb);
        ra = fmaf(xra[5], u1[1], ra);  rb = fmaf(xrb[5], u1[1], rb);
        ra = fmaf(xra[6], u1[2], ra);  rb = fmaf(xrb[6], u1[2], rb);
        ra = fmaf(xra[7], u1[3], ra);  rb = fmaf(xrb[7], u1[3], rb);
        aa[o] = wave_reduce_sum63(ra);   // independent 6-step DPP chains
        ab[o] = wave_reduce_sum63(rb);
    }
    if (lane == 63) {
        const float* bp = params + (size_t)i * P_TOTAL + 18368;
        float m = -3.4e38f;
#pragma unroll
        for (int o = 0; o < 10; ++o) { aa[o] += bp[o]; m = fmaxf(m, aa[o]); }
        float ssum = 0.f;
#pragma unroll
        for (int o = 0; o < 10; ++o) ssum += __expf(aa[o] - m);
        float ls = __logf(ssum) + m;
        float* op = out + ((size_t)i * 128 + j0) * 10;
#pragma unroll
        for (int o = 0; o < 10; ++o) op[o] = aa[o] - ls;

        m = -3.4e38f;
#pragma unroll
        for (int o = 0; o < 10; ++o) { ab[o] += bp[o]; m = fmaxf(m, ab[o]); }
        ssum = 0.f;
#pragma unroll
        for (int o = 0; o < 10; ++o) ssum += __expf(ab[o] - m);
        ls = __logf(ssum) + m;
        op = out + ((size_t)i * 128 + j1) * 10;
#pragma unroll
        for (int o = 0; o < 10; ++o) op[o] = ab[o] - ls;
    }
}

extern "C" void kernel_launch(void* const* d_in, const int* in_sizes, int n_in,
                              void* d_out, int out_size, void* d_ws, size_t ws_size,
                              hipStream_t stream) {
    const float* params = (const float*)d_in[0];   // (64, 18378) fp32
    const float* batch  = (const float*)d_in[1];   // (128, 1, 28, 28) fp32
    float* out = (float*)d_out;                    // (64, 128, 10) fp32

    // workspace (16B-aligned sections):
    //   wswz 64*12800 bf16 = 1,638,400 B
    //   w3lf 64*5120  f32  = 1,310,720 B
    //   w1bf 64*512   bf16 =    65,536 B
    //   Bmat 128*18432 bf16 = 4,718,592 B
    unsigned short* wswz = (unsigned short*)d_ws;
    float* w3lf = (float*)((char*)d_ws + 1638400);
    unsigned short* w1bf = (unsigned short*)((char*)d_ws + 1638400 + 1310720);
    unsigned short* Bmat = (unsigned short*)((char*)d_ws + 1638400 + 1310720 + 65536);

    prep_kernel<<<768, 256, 0, stream>>>(params, batch, wswz, w3lf, w1bf, Bmat);
    // R18 grid: 1024 blocks = 64 inits x 16 image-groups(8), I-FAST (i = b&63,
    // R15's measured-best mapping); 4 waves/block, each wave = 2 images;
    // 4 blocks/CU (LDS 36.9 KB, VGPR<=128).
    mega_kernel<<<1024, 256, 0, stream>>>(params, Bmat, w1bf, wswz, w3lf, out);
}